// Round 1
// baseline (240.753 us; speedup 1.0000x reference)
//
#include <hip/hip_runtime.h>

#define NGRAPHS 2048
#define DIN     1536
#define DH1     64
#define DH2     32

// Pass 1: batch is sorted, so graph g occupies rows [offsets[g], offsets[g+1]).
// offsets[g] = lower_bound(batch, g). Each thread i fills the offsets slots for
// graph ids that START at row i; thread n-1 also closes out trailing empties.
__global__ void find_offsets_kernel(const int* __restrict__ batch, int n,
                                    int* __restrict__ offsets) {
    int i = blockIdx.x * blockDim.x + threadIdx.x;
    if (i >= n) return;
    int b = batch[i];
    int prev = (i == 0) ? -1 : batch[i - 1];
    for (int g = prev + 1; g <= b; ++g) offsets[g] = i;
    if (i == n - 1) {
        for (int g = b + 1; g <= NGRAPHS; ++g) offsets[g] = n;
    }
}

// Pass 2: one block per graph. 384 threads x float4 = 1536 columns.
// Coalesced streaming sum of the graph's rows -> mean in LDS -> tiny MLP.
__global__ __launch_bounds__(384) void pool_mlp_kernel(
    const float* __restrict__ features,
    const int* __restrict__ offsets,
    const float* __restrict__ W1, const float* __restrict__ b1,
    const float* __restrict__ W2, const float* __restrict__ b2,
    const float* __restrict__ W3, const float* __restrict__ b3,
    float* __restrict__ out)
{
    const int g   = blockIdx.x;
    const int tid = threadIdx.x;
    const int s   = offsets[g];
    const int e   = offsets[g + 1];

    __shared__ float mean_s[DIN];
    __shared__ float h1_s[DH1];
    __shared__ float h2_s[DH2];

    // ---- segment sum (coalesced: lane i reads float4 at column 4*i) ----
    float4 acc = make_float4(0.f, 0.f, 0.f, 0.f);
    const float4* __restrict__ F4 = reinterpret_cast<const float4*>(features);
    for (int r = s; r < e; ++r) {
        float4 v = F4[(size_t)r * (DIN / 4) + tid];
        acc.x += v.x; acc.y += v.y; acc.z += v.z; acc.w += v.w;
    }
    const float inv = 1.0f / (float)((e - s) > 1 ? (e - s) : 1);
    acc.x *= inv; acc.y *= inv; acc.z *= inv; acc.w *= inv;
    reinterpret_cast<float4*>(mean_s)[tid] = acc;
    __syncthreads();

    // ---- layer 1: h1[j] = relu(b1[j] + mean . W1[j,:]) ----
    if (tid < DH1) {
        const float4* __restrict__ w4 =
            reinterpret_cast<const float4*>(W1 + (size_t)tid * DIN);
        const float4* __restrict__ m4 = reinterpret_cast<const float4*>(mean_s);
        float a = b1[tid];
        #pragma unroll 8
        for (int k = 0; k < DIN / 4; ++k) {
            float4 w = w4[k];
            float4 m = m4[k];
            a += m.x * w.x + m.y * w.y + m.z * w.z + m.w * w.w;
        }
        h1_s[tid] = fmaxf(a, 0.f);
    }
    __syncthreads();

    // ---- layer 2: h2[j] = relu(b2[j] + h1 . W2[j,:]) ----
    if (tid < DH2) {
        const float* __restrict__ w = W2 + (size_t)tid * DH1;
        float a = b2[tid];
        #pragma unroll
        for (int i = 0; i < DH1; ++i) a += h1_s[i] * w[i];
        h2_s[tid] = fmaxf(a, 0.f);
    }
    __syncthreads();

    // ---- layer 3: out[g] = b3 + h2 . W3[0,:] ----
    if (tid == 0) {
        float a = b3[0];
        #pragma unroll
        for (int j = 0; j < DH2; ++j) a += h2_s[j] * W3[j];
        out[g] = a;
    }
}

extern "C" void kernel_launch(void* const* d_in, const int* in_sizes, int n_in,
                              void* d_out, int out_size, void* d_ws, size_t ws_size,
                              hipStream_t stream) {
    const float* features = (const float*)d_in[0];
    const int*   batch    = (const int*)d_in[1];   // int64 in ref -> int32 here (x64 off)
    const float* W1 = (const float*)d_in[2];
    const float* b1 = (const float*)d_in[3];
    const float* W2 = (const float*)d_in[4];
    const float* b2 = (const float*)d_in[5];
    const float* W3 = (const float*)d_in[6];
    const float* b3 = (const float*)d_in[7];
    float* out = (float*)d_out;

    const int n = in_sizes[1];           // 131072 rows
    int* offsets = (int*)d_ws;           // (NGRAPHS+1) ints, rewritten every call

    find_offsets_kernel<<<(n + 255) / 256, 256, 0, stream>>>(batch, n, offsets);
    pool_mlp_kernel<<<NGRAPHS, 384, 0, stream>>>(features, offsets,
                                                 W1, b1, W2, b2, W3, b3, out);
}

// Round 2
// 223.776 us; speedup vs baseline: 1.0759x; 1.0759x over previous
//
#include <hip/hip_runtime.h>

#define NGRAPHS 2048
#define DIN     1536
#define DH1     64
#define DH2     32

// Pass 1: batch is sorted, so graph g occupies rows [offsets[g], offsets[g+1]).
// offsets[g] = lower_bound(batch, g). Each thread i fills the offsets slots for
// graph ids that START at row i; thread n-1 also closes out trailing empties.
__global__ void find_offsets_kernel(const int* __restrict__ batch, int n,
                                    int* __restrict__ offsets) {
    int i = blockIdx.x * blockDim.x + threadIdx.x;
    if (i >= n) return;
    int b = batch[i];
    int prev = (i == 0) ? -1 : batch[i - 1];
    for (int g = prev + 1; g <= b; ++g) offsets[g] = i;
    if (i == n - 1) {
        for (int g = b + 1; g <= NGRAPHS; ++g) offsets[g] = n;
    }
}

// Pass 2: one block per graph. 384 threads x float4 = 1536 columns.
// Row loop unrolled x4 with independent accumulators: 4 outstanding
// global_load_dwordx4 per lane instead of 1 -> covers HBM latency (G7 ILP).
__global__ __launch_bounds__(384) void pool_mlp_kernel(
    const float* __restrict__ features,
    const int* __restrict__ offsets,
    const float* __restrict__ W1, const float* __restrict__ b1,
    const float* __restrict__ W2, const float* __restrict__ b2,
    const float* __restrict__ W3, const float* __restrict__ b3,
    float* __restrict__ out)
{
    const int g   = blockIdx.x;
    const int tid = threadIdx.x;
    const int s   = offsets[g];
    const int e   = offsets[g + 1];

    __shared__ float mean_s[DIN];
    __shared__ float h1_s[DH1];
    __shared__ float h2_s[DH2];

    const float4* __restrict__ F4 = reinterpret_cast<const float4*>(features);

    float4 a0 = make_float4(0.f, 0.f, 0.f, 0.f);
    float4 a1 = make_float4(0.f, 0.f, 0.f, 0.f);
    float4 a2 = make_float4(0.f, 0.f, 0.f, 0.f);
    float4 a3 = make_float4(0.f, 0.f, 0.f, 0.f);

    int r = s;
    for (; r + 4 <= e; r += 4) {
        float4 v0 = F4[(size_t)(r + 0) * (DIN / 4) + tid];
        float4 v1 = F4[(size_t)(r + 1) * (DIN / 4) + tid];
        float4 v2 = F4[(size_t)(r + 2) * (DIN / 4) + tid];
        float4 v3 = F4[(size_t)(r + 3) * (DIN / 4) + tid];
        a0.x += v0.x; a0.y += v0.y; a0.z += v0.z; a0.w += v0.w;
        a1.x += v1.x; a1.y += v1.y; a1.z += v1.z; a1.w += v1.w;
        a2.x += v2.x; a2.y += v2.y; a2.z += v2.z; a2.w += v2.w;
        a3.x += v3.x; a3.y += v3.y; a3.z += v3.z; a3.w += v3.w;
    }
    for (; r < e; ++r) {
        float4 v = F4[(size_t)r * (DIN / 4) + tid];
        a0.x += v.x; a0.y += v.y; a0.z += v.z; a0.w += v.w;
    }
    a0.x += a1.x + a2.x + a3.x;
    a0.y += a1.y + a2.y + a3.y;
    a0.z += a1.z + a2.z + a3.z;
    a0.w += a1.w + a2.w + a3.w;

    const int cnt = e - s;
    const float inv = 1.0f / (float)(cnt > 1 ? cnt : 1);
    a0.x *= inv; a0.y *= inv; a0.z *= inv; a0.w *= inv;
    reinterpret_cast<float4*>(mean_s)[tid] = a0;
    __syncthreads();

    // ---- layer 1: h1[j] = relu(b1[j] + mean . W1[j,:]) ----
    if (tid < DH1) {
        const float4* __restrict__ w4 =
            reinterpret_cast<const float4*>(W1 + (size_t)tid * DIN);
        const float4* __restrict__ m4 = reinterpret_cast<const float4*>(mean_s);
        float a = b1[tid];
        #pragma unroll 8
        for (int k = 0; k < DIN / 4; ++k) {
            float4 w = w4[k];
            float4 m = m4[k];
            a += m.x * w.x + m.y * w.y + m.z * w.z + m.w * w.w;
        }
        h1_s[tid] = fmaxf(a, 0.f);
    }
    __syncthreads();

    // ---- layer 2: h2[j] = relu(b2[j] + h1 . W2[j,:]) ----
    if (tid < DH2) {
        const float* __restrict__ w = W2 + (size_t)tid * DH1;
        float a = b2[tid];
        #pragma unroll
        for (int i = 0; i < DH1; ++i) a += h1_s[i] * w[i];
        h2_s[tid] = fmaxf(a, 0.f);
    }
    __syncthreads();

    // ---- layer 3: out[g] = b3 + h2 . W3[0,:] ----
    if (tid == 0) {
        float a = b3[0];
        #pragma unroll
        for (int j = 0; j < DH2; ++j) a += h2_s[j] * W3[j];
        out[g] = a;
    }
}

extern "C" void kernel_launch(void* const* d_in, const int* in_sizes, int n_in,
                              void* d_out, int out_size, void* d_ws, size_t ws_size,
                              hipStream_t stream) {
    const float* features = (const float*)d_in[0];
    const int*   batch    = (const int*)d_in[1];   // int64 in ref -> int32 here (x64 off)
    const float* W1 = (const float*)d_in[2];
    const float* b1 = (const float*)d_in[3];
    const float* W2 = (const float*)d_in[4];
    const float* b2 = (const float*)d_in[5];
    const float* W3 = (const float*)d_in[6];
    const float* b3 = (const float*)d_in[7];
    float* out = (float*)d_out;

    const int n = in_sizes[1];           // 131072 rows
    int* offsets = (int*)d_ws;           // (NGRAPHS+1) ints, rewritten every call

    find_offsets_kernel<<<(n + 255) / 256, 256, 0, stream>>>(batch, n, offsets);
    pool_mlp_kernel<<<NGRAPHS, 384, 0, stream>>>(features, offsets,
                                                 W1, b1, W2, b2, W3, b3, out);
}

// Round 3
// 176.561 us; speedup vs baseline: 1.3636x; 1.2674x over previous
//
#include <hip/hip_runtime.h>

#define NGRAPHS 2048
#define DIN     1536
#define DH1     64
#define DH2     32

// Pass 1: batch is sorted, so graph g occupies rows [offsets[g], offsets[g+1]).
__global__ void find_offsets_kernel(const int* __restrict__ batch, int n,
                                    int* __restrict__ offsets) {
    int i = blockIdx.x * blockDim.x + threadIdx.x;
    if (i >= n) return;
    int b = batch[i];
    int prev = (i == 0) ? -1 : batch[i - 1];
    for (int g = prev + 1; g <= b; ++g) offsets[g] = i;
    if (i == n - 1) {
        for (int g = b + 1; g <= NGRAPHS; ++g) offsets[g] = n;
    }
}

// Pass 2: one block per graph. 384 threads x float4 = 1536 columns.
// Pool: coalesced streaming sum (x4 row unroll for ILP).
// MLP: wave-cooperative layers — weights read COALESCED (contiguous per wave),
// shuffle-reduce dot products. Avoids the 64-line-per-load W1 gather and the
// 384-deep dependent FMA chain of the thread-per-output version.
__global__ __launch_bounds__(384) void pool_mlp_kernel(
    const float* __restrict__ features,
    const int* __restrict__ offsets,
    const float* __restrict__ W1, const float* __restrict__ b1,
    const float* __restrict__ W2, const float* __restrict__ b2,
    const float* __restrict__ W3, const float* __restrict__ b3,
    float* __restrict__ out)
{
    const int g    = blockIdx.x;
    const int tid  = threadIdx.x;
    const int lane = tid & 63;
    const int wave = tid >> 6;          // 6 waves

    const int s = offsets[g];
    const int e = offsets[g + 1];

    __shared__ float mean_s[DIN];
    __shared__ float h1_s[DH1];
    __shared__ float h2_s[DH2];

    // ---- segment mean (coalesced: lane i reads float4 at column 4*i) ----
    const float4* __restrict__ F4 = reinterpret_cast<const float4*>(features);
    float4 a0 = make_float4(0.f, 0.f, 0.f, 0.f);
    float4 a1 = make_float4(0.f, 0.f, 0.f, 0.f);
    float4 a2 = make_float4(0.f, 0.f, 0.f, 0.f);
    float4 a3 = make_float4(0.f, 0.f, 0.f, 0.f);

    int r = s;
    for (; r + 4 <= e; r += 4) {
        float4 v0 = F4[(size_t)(r + 0) * (DIN / 4) + tid];
        float4 v1 = F4[(size_t)(r + 1) * (DIN / 4) + tid];
        float4 v2 = F4[(size_t)(r + 2) * (DIN / 4) + tid];
        float4 v3 = F4[(size_t)(r + 3) * (DIN / 4) + tid];
        a0.x += v0.x; a0.y += v0.y; a0.z += v0.z; a0.w += v0.w;
        a1.x += v1.x; a1.y += v1.y; a1.z += v1.z; a1.w += v1.w;
        a2.x += v2.x; a2.y += v2.y; a2.z += v2.z; a2.w += v2.w;
        a3.x += v3.x; a3.y += v3.y; a3.z += v3.z; a3.w += v3.w;
    }
    for (; r < e; ++r) {
        float4 v = F4[(size_t)r * (DIN / 4) + tid];
        a0.x += v.x; a0.y += v.y; a0.z += v.z; a0.w += v.w;
    }
    a0.x += a1.x + a2.x + a3.x;
    a0.y += a1.y + a2.y + a3.y;
    a0.z += a1.z + a2.z + a3.z;
    a0.w += a1.w + a2.w + a3.w;

    const int cnt = e - s;
    const float inv = 1.0f / (float)(cnt > 1 ? cnt : 1);
    a0.x *= inv; a0.y *= inv; a0.z *= inv; a0.w *= inv;
    reinterpret_cast<float4*>(mean_s)[tid] = a0;
    __syncthreads();

    // ---- layer 1: wave-cooperative dot per output, coalesced W1 reads ----
    const float4* __restrict__ m4 = reinterpret_cast<const float4*>(mean_s);
    for (int j = wave; j < DH1; j += 6) {
        const float4* __restrict__ w4 =
            reinterpret_cast<const float4*>(W1 + (size_t)j * DIN);
        float acc = 0.f;
        #pragma unroll
        for (int k = 0; k < DIN / 4 / 64; ++k) {          // 6 iterations
            float4 w = w4[k * 64 + lane];                  // contiguous 1KB/wave
            float4 m = m4[k * 64 + lane];                  // contiguous LDS
            acc += m.x * w.x + m.y * w.y + m.z * w.z + m.w * w.w;
        }
        #pragma unroll
        for (int off = 32; off; off >>= 1) acc += __shfl_xor(acc, off, 64);
        if (lane == 0) h1_s[j] = fmaxf(acc + b1[j], 0.f);
    }
    __syncthreads();

    // ---- layer 2: wave-cooperative, dot length 64 == wave width ----
    for (int j = wave; j < DH2; j += 6) {
        float acc = h1_s[lane] * W2[(size_t)j * DH1 + lane];  // 256B coalesced
        #pragma unroll
        for (int off = 32; off; off >>= 1) acc += __shfl_xor(acc, off, 64);
        if (lane == 0) h2_s[j] = fmaxf(acc + b2[j], 0.f);
    }
    __syncthreads();

    // ---- layer 3 ----
    if (wave == 0) {
        float acc = (lane < DH2) ? h2_s[lane] * W3[lane] : 0.f;
        #pragma unroll
        for (int off = 32; off; off >>= 1) acc += __shfl_xor(acc, off, 64);
        if (lane == 0) out[g] = acc + b3[0];
    }
}

extern "C" void kernel_launch(void* const* d_in, const int* in_sizes, int n_in,
                              void* d_out, int out_size, void* d_ws, size_t ws_size,
                              hipStream_t stream) {
    const float* features = (const float*)d_in[0];
    const int*   batch    = (const int*)d_in[1];   // int64 in ref -> int32 here (x64 off)
    const float* W1 = (const float*)d_in[2];
    const float* b1 = (const float*)d_in[3];
    const float* W2 = (const float*)d_in[4];
    const float* b2 = (const float*)d_in[5];
    const float* W3 = (const float*)d_in[6];
    const float* b3 = (const float*)d_in[7];
    float* out = (float*)d_out;

    const int n = in_sizes[1];           // 131072 rows
    int* offsets = (int*)d_ws;           // (NGRAPHS+1) ints, rewritten every call

    find_offsets_kernel<<<(n + 255) / 256, 256, 0, stream>>>(batch, n, offsets);
    pool_mlp_kernel<<<NGRAPHS, 384, 0, stream>>>(features, offsets,
                                                 W1, b1, W2, b2, W3, b3, out);
}